// Round 1
// baseline (147.074 us; speedup 1.0000x reference)
//
#include <hip/hip_runtime.h>
#include <hip/hip_cooperative_groups.h>

namespace cg = cooperative_groups;

#define N_NODES 50000
#define N_EDGES 800000
#define EN      (N_EDGES + N_NODES)
#define F_IN    128
#define HC      64    // HEADS * C_OUT
#define NEG_SLOPE 0.2f
#define NBUCK   196   // ceil(50000/256) buckets of 256 nodes
#define BCAP    5120  // per-bucket capacity in srcs
#define LIN_BLOCKS 782               // ceil(50000/64) -- 64 rows/block (MFMA)
#define XPAD    136                  // LDS row stride in shorts (2-way conflicts only)
#define MEGA_GRID 1024               // 4 blocks/CU co-resident (launch_bounds 256,4)
#define NAGG    (N_NODES / 16)       // 3125 aggregation units of 16 dsts
#define NPAIR   (EN / 2)             // 425000 edge pairs for alpha

typedef __attribute__((ext_vector_type(8))) short bf16x8;
typedef __attribute__((ext_vector_type(4))) float f32x4;

static __device__ __forceinline__ unsigned short f2bf(float f) {   // RNE f32->bf16
    unsigned int b = __float_as_uint(f);
    return (unsigned short)((b + 0x7FFFu + ((b >> 16) & 1u)) >> 16);
}

// ---------------- KA: h=x@W via bf16 MFMA + a_src/a_dst (linear only now) --------
__global__ __launch_bounds__(256) void
kA_linear(const float* __restrict__ x, const float* __restrict__ W,
          const float* __restrict__ att_src, const float* __restrict__ att_dst,
          unsigned short* __restrict__ hbf, float* __restrict__ a_src,
          float* __restrict__ a_dst) {
    __shared__ unsigned short xs[64][XPAD];      // 17.4 KB bf16 x-tile
    __shared__ unsigned short wt[64][XPAD];      // 17.4 KB bf16 W^T (col-major W)
    const int tid = threadIdx.x;

    const int wv   = tid >> 6;
    const int l    = tid & 63;
    const int base = blockIdx.x * 64;
    const int c16  = l & 15;        // MFMA non-K lane index
    const int grp  = l >> 4;        // K-group / C row-group

    // stage W transposed as bf16: wt[col][k]  (8 coalesced float4 loads/thread)
    #pragma unroll
    for (int it = 0; it < 8; ++it) {
        int f  = it * 1024 + tid * 4;   // covers 128*64 = 8192 floats
        int k  = f >> 6;                // W row (K index)
        int cl = f & 63;                // W col
        float4 v = *(const float4*)(W + (size_t)k * HC + cl);
        wt[cl + 0][k] = f2bf(v.x);
        wt[cl + 1][k] = f2bf(v.y);
        wt[cl + 2][k] = f2bf(v.z);
        wt[cl + 3][k] = f2bf(v.w);
    }

    // stage x-tile (64 x 128) as bf16
    #pragma unroll
    for (int it = 0; it < 8; ++it) {
        int f   = it * 1024 + tid * 4;
        int row = f >> 7, k = f & 127;
        int gr  = base + row;
        float4 v = {0.f, 0.f, 0.f, 0.f};
        if (gr < N_NODES) v = *(const float4*)(x + (size_t)gr * F_IN + k);
        ushort4 u = {f2bf(v.x), f2bf(v.y), f2bf(v.z), f2bf(v.w)};
        *(ushort4*)(&xs[row][k]) = u;
    }
    __syncthreads();

    // B-frags via ds_read_b128: lane col=c16 of tile t, k=kk*32+grp*8..+7
    bf16x8 Bf[4][4];
    #pragma unroll
    for (int t = 0; t < 4; ++t)
        #pragma unroll
        for (int kk = 0; kk < 4; ++kk)
            Bf[t][kk] = *(const bf16x8*)(&wt[t * 16 + c16][kk * 32 + grp * 8]);

    // A-frags for this wave's 16 rows: lane row=c16, k=kk*32+grp*8..+7
    const int r0 = wv * 16;
    f32x4 C[4];
    #pragma unroll
    for (int t = 0; t < 4; ++t) C[t] = (f32x4){0.f, 0.f, 0.f, 0.f};
    bf16x8 A[4];
    #pragma unroll
    for (int kk = 0; kk < 4; ++kk)
        A[kk] = *(const bf16x8*)(&xs[r0 + c16][kk * 32 + grp * 8]);
    #pragma unroll
    for (int t = 0; t < 4; ++t)
        #pragma unroll
        for (int kk = 0; kk < 4; ++kk)
            C[t] = __builtin_amdgcn_mfma_f32_16x16x32_bf16(A[kk], Bf[t][kk], C[t], 0, 0, 0);

    // epilogue: C lane holds rows grp*4+j, col t*16+c16
    float asv[4], adv[4];
    #pragma unroll
    for (int t = 0; t < 4; ++t) {
        asv[t] = att_src[t * 16 + c16];
        adv[t] = att_dst[t * 16 + c16];
    }
    #pragma unroll
    for (int j = 0; j < 4; ++j) {
        const int row = base + r0 + grp * 4 + j;
        const bool ok = row < N_NODES;
        float4 ta, td;
        float* tap = (float*)&ta;
        float* tdp = (float*)&td;
        #pragma unroll
        for (int t = 0; t < 4; ++t) {
            const float hv = C[t][j];
            if (ok) hbf[(size_t)row * HC + t * 16 + c16] = f2bf(hv);
            float ts = hv * asv[t];
            float tdv = hv * adv[t];
            #pragma unroll
            for (int m = 1; m < 16; m <<= 1) {
                ts  += __shfl_xor(ts, m);
                tdv += __shfl_xor(tdv, m);
            }
            tap[t] = ts;
            tdp[t] = tdv;
        }
        if (ok && c16 == 0) {
            *(float4*)(a_src + row * 4) = ta;
            *(float4*)(a_dst + row * 4) = td;
        }
    }
}

// =============== phase device functions (shared by mega + fallback) ===============

static __device__ __forceinline__ void
phase_zero(int* __restrict__ deg, int gsz, int gtid) {
    for (int i = gtid; i < N_NODES; i += gsz) deg[i] = 0;
}

static __device__ __forceinline__ void
phase_count(const int* __restrict__ ei, int* __restrict__ deg, int gsz, int gtid) {
    // N_EDGES even: int2 over the dst half
    for (int e2 = gtid; e2 < N_EDGES / 2; e2 += gsz) {
        int2 dp = *(const int2*)(ei + N_EDGES + e2 * 2);
        atomicAdd(&deg[dp.x], 1);
        atomicAdd(&deg[dp.y], 1);
    }
}

static __device__ __forceinline__ void
phase_scan(const int* __restrict__ deg, int* __restrict__ row_info,
           int* __restrict__ srcs, int* __restrict__ cur, int* sm,
           int b, int tid) {
    const int node = (b << 8) + tid;
    int v = 0;
    if (node < N_NODES) v = deg[node] + 1;   // +1 = self-loop
    sm[tid] = v;
    __syncthreads();
    for (int off = 1; off < 256; off <<= 1) {
        int t = (tid >= off) ? sm[tid - off] : 0;
        __syncthreads();
        sm[tid] += t;
        __syncthreads();
    }
    const int ex = sm[tid] - v;
    const int sbase = b * BCAP;
    if (node < N_NODES) {
        row_info[node] = ((sbase + ex) << 8) | v;   // deg+1 <= 255
        srcs[sbase + ex] = node;                    // self-loop at segment head
        cur[node] = sbase + ex + 1;
    }
}

static __device__ __forceinline__ void
phase_scatter(const int* __restrict__ ei, int* __restrict__ cur,
              int* __restrict__ srcs, int gsz, int gtid) {
    for (int e2 = gtid; e2 < N_EDGES / 2; e2 += gsz) {
        int2 sp = *(const int2*)(ei + e2 * 2);
        int2 dp = *(const int2*)(ei + N_EDGES + e2 * 2);
        int p0 = atomicAdd(&cur[dp.x], 1);
        srcs[p0] = sp.x;
        int p1 = atomicAdd(&cur[dp.y], 1);
        srcs[p1] = sp.y;
    }
}

static __device__ __forceinline__ void
phase_agg(const int* __restrict__ row_info, const int* __restrict__ srcs,
          const float* __restrict__ a_src, const float* __restrict__ a_dst,
          const unsigned int* __restrict__ hw, const float* __restrict__ bias,
          float* __restrict__ out, float* __restrict__ s_inv,
          int (*s_lds)[4][16], float (*p_lds)[4][16][4],
          int nblk, int bid, int tid) {
    const int wv   = tid >> 6;
    const int lane = tid & 63;
    const int g    = lane >> 4;
    const int l    = lane & 15;
    const int hd   = l >> 2;

    for (int u = bid; u < NAGG; u += nblk) {
        const int d = u * 16 + wv * 4 + g;

        const int info   = row_info[d];
        const int begin  = info >> 8;
        const int cnt    = info & 255;
        const int nchunk = (cnt + 15) >> 4;
        const float4 ad  = *(const float4*)(a_dst + d * 4);

        float4 ps = {0.f, 0.f, 0.f, 0.f};
        float a0 = 0.f, a1 = 0.f, a2 = 0.f, a3 = 0.f;

        for (int c = 0; c < nchunk; ++c) {
            const int k0 = begin + c * 16;
            const int m  = min(16, begin + cnt - k0);
            const int s = srcs[k0 + (l < m ? l : m - 1)];  // dup-src padding
            float4 p = {0.f, 0.f, 0.f, 0.f};
            if (l < m) {
                float4 as = *(const float4*)(a_src + s * 4);
                float e0 = as.x + ad.x, e1 = as.y + ad.y, e2 = as.z + ad.z, e3 = as.w + ad.w;
                e0 = e0 > 0.f ? e0 : NEG_SLOPE * e0;
                e1 = e1 > 0.f ? e1 : NEG_SLOPE * e1;
                e2 = e2 > 0.f ? e2 : NEG_SLOPE * e2;
                e3 = e3 > 0.f ? e3 : NEG_SLOPE * e3;
                p.x = __expf(e0); p.y = __expf(e1); p.z = __expf(e2); p.w = __expf(e3);
                ps.x += p.x; ps.y += p.y; ps.z += p.z; ps.w += p.w;
            }
            s_lds[wv][g][l] = s;
            *(float4*)(&p_lds[wv][g][l][0]) = p;
            __threadfence_block();

            const int mp = (m + 3) & ~3;                 // padded count (4,8,12,16)
            for (int e = 0; e < mp; e += 4) {
                int s0 = s_lds[wv][g][e + 0], s1 = s_lds[wv][g][e + 1];
                int s2 = s_lds[wv][g][e + 2], s3 = s_lds[wv][g][e + 3];
                float p0 = p_lds[wv][g][e + 0][hd], p1 = p_lds[wv][g][e + 1][hd];
                float p2 = p_lds[wv][g][e + 2][hd], p3 = p_lds[wv][g][e + 3][hd];
                uint2 u0 = *(const uint2*)(hw + (size_t)s0 * 32 + l * 2);
                uint2 u1 = *(const uint2*)(hw + (size_t)s1 * 32 + l * 2);
                uint2 u2 = *(const uint2*)(hw + (size_t)s2 * 32 + l * 2);
                uint2 u3 = *(const uint2*)(hw + (size_t)s3 * 32 + l * 2);
                a0 += __uint_as_float(u0.x << 16)         * p0;
                a1 += __uint_as_float(u0.x & 0xFFFF0000u) * p0;
                a2 += __uint_as_float(u0.y << 16)         * p0;
                a3 += __uint_as_float(u0.y & 0xFFFF0000u) * p0;
                a0 += __uint_as_float(u1.x << 16)         * p1;
                a1 += __uint_as_float(u1.x & 0xFFFF0000u) * p1;
                a2 += __uint_as_float(u1.y << 16)         * p1;
                a3 += __uint_as_float(u1.y & 0xFFFF0000u) * p1;
                a0 += __uint_as_float(u2.x << 16)         * p2;
                a1 += __uint_as_float(u2.x & 0xFFFF0000u) * p2;
                a2 += __uint_as_float(u2.y << 16)         * p2;
                a3 += __uint_as_float(u2.y & 0xFFFF0000u) * p2;
                a0 += __uint_as_float(u3.x << 16)         * p3;
                a1 += __uint_as_float(u3.x & 0xFFFF0000u) * p3;
                a2 += __uint_as_float(u3.y << 16)         * p3;
                a3 += __uint_as_float(u3.y & 0xFFFF0000u) * p3;
            }
            __threadfence_block();
        }

        #pragma unroll
        for (int mm = 1; mm < 16; mm <<= 1) {
            ps.x += __shfl_xor(ps.x, mm);
            ps.y += __shfl_xor(ps.y, mm);
            ps.z += __shfl_xor(ps.z, mm);
            ps.w += __shfl_xor(ps.w, mm);
        }
        const float4 inv = {1.f / (ps.x + 1e-16f), 1.f / (ps.y + 1e-16f),
                            1.f / (ps.z + 1e-16f), 1.f / (ps.w + 1e-16f)};
        if (l == 0) *(float4*)(s_inv + d * 4) = inv;

        const float invh = (hd == 0) ? inv.x : (hd == 1) ? inv.y : (hd == 2) ? inv.z : inv.w;
        float4 o;
        o.x = a0 * invh + bias[l * 4 + 0];
        o.y = a1 * invh + bias[l * 4 + 1];
        o.z = a2 * invh + bias[l * 4 + 2];
        o.w = a3 * invh + bias[l * 4 + 3];
        *(float4*)(out + (size_t)d * HC + l * 4) = o;
    }
}

static __device__ __forceinline__ void
phase_alpha(const int* __restrict__ ei, const float* __restrict__ a_src,
            const float* __restrict__ a_dst, const float* __restrict__ s_inv,
            float* __restrict__ alpha_out, int gsz, int gtid) {
    for (int i2 = gtid; i2 < NPAIR; i2 += gsz) {
        const int i = i2 * 2;
        int s0, s1, d0, d1;
        if (i < N_EDGES) {                        // N_EDGES even: pair never straddles
            int2 sp = *(const int2*)(ei + i);
            int2 dp = *(const int2*)(ei + N_EDGES + i);
            s0 = sp.x; s1 = sp.y; d0 = dp.x; d1 = dp.y;
        } else {
            s0 = d0 = i - N_EDGES;
            s1 = d1 = i + 1 - N_EDGES;
        }

        float4 as0 = *(const float4*)(a_src + s0 * 4);
        float4 ad0 = *(const float4*)(a_dst + d0 * 4);
        float4 iv0 = *(const float4*)(s_inv + d0 * 4);
        float4 as1 = *(const float4*)(a_src + s1 * 4);
        float4 ad1 = *(const float4*)(a_dst + d1 * 4);
        float4 iv1 = *(const float4*)(s_inv + d1 * 4);

        float e0, e1, e2, e3;
        e0 = as0.x + ad0.x; e1 = as0.y + ad0.y; e2 = as0.z + ad0.z; e3 = as0.w + ad0.w;
        e0 = e0 > 0.f ? e0 : NEG_SLOPE * e0;
        e1 = e1 > 0.f ? e1 : NEG_SLOPE * e1;
        e2 = e2 > 0.f ? e2 : NEG_SLOPE * e2;
        e3 = e3 > 0.f ? e3 : NEG_SLOPE * e3;
        float4 al0 = {__expf(e0) * iv0.x, __expf(e1) * iv0.y,
                      __expf(e2) * iv0.z, __expf(e3) * iv0.w};
        e0 = as1.x + ad1.x; e1 = as1.y + ad1.y; e2 = as1.z + ad1.z; e3 = as1.w + ad1.w;
        e0 = e0 > 0.f ? e0 : NEG_SLOPE * e0;
        e1 = e1 > 0.f ? e1 : NEG_SLOPE * e1;
        e2 = e2 > 0.f ? e2 : NEG_SLOPE * e2;
        e3 = e3 > 0.f ? e3 : NEG_SLOPE * e3;
        float4 al1 = {__expf(e0) * iv1.x, __expf(e1) * iv1.y,
                      __expf(e2) * iv1.z, __expf(e3) * iv1.w};

        *(float4*)(alpha_out + (size_t)i * 4)     = al0;
        *(float4*)(alpha_out + (size_t)i * 4 + 4) = al1;
    }
}

// ---------------- MEGA: cooperative fused pipeline (zero..alpha) ----------------
__global__ __launch_bounds__(256, 4) void
mega(const int* __restrict__ ei, const float* __restrict__ a_src,
     const float* __restrict__ a_dst, const unsigned int* __restrict__ hw,
     const float* __restrict__ bias, float* __restrict__ out,
     float* __restrict__ s_inv, int* __restrict__ deg, int* __restrict__ cur,
     int* __restrict__ row_info, int* __restrict__ srcs,
     float* __restrict__ alpha_out) {
    __shared__ int   sm[256];
    __shared__ int   s_lds[4][4][16];
    __shared__ float p_lds[4][4][16][4];

    cg::grid_group grid = cg::this_grid();
    const int tid  = threadIdx.x;
    const int bid  = blockIdx.x;
    const int gsz  = (int)gridDim.x << 8;
    const int gtid = (bid << 8) + tid;

    phase_zero(deg, gsz, gtid);
    grid.sync();
    phase_count(ei, deg, gsz, gtid);
    grid.sync();
    if (bid < NBUCK) phase_scan(deg, row_info, srcs, cur, sm, bid, tid);
    grid.sync();
    phase_scatter(ei, cur, srcs, gsz, gtid);
    grid.sync();
    phase_agg(row_info, srcs, a_src, a_dst, hw, bias, out, s_inv,
              s_lds, p_lds, (int)gridDim.x, bid, tid);
    grid.sync();
    phase_alpha(ei, a_src, a_dst, s_inv, alpha_out, gsz, gtid);
}

// ---------------- fallback (non-cooperative) kernels ----------------
__global__ __launch_bounds__(256) void k_zero(int* deg) {
    phase_zero(deg, gridDim.x << 8, (blockIdx.x << 8) + threadIdx.x);
}
__global__ __launch_bounds__(256) void k_count(const int* ei, int* deg) {
    phase_count(ei, deg, gridDim.x << 8, (blockIdx.x << 8) + threadIdx.x);
}
__global__ __launch_bounds__(256) void
k_scan(const int* deg, int* row_info, int* srcs, int* cur) {
    __shared__ int sm[256];
    phase_scan(deg, row_info, srcs, cur, sm, blockIdx.x, threadIdx.x);
}
__global__ __launch_bounds__(256) void k_scatter(const int* ei, int* cur, int* srcs) {
    phase_scatter(ei, cur, srcs, gridDim.x << 8, (blockIdx.x << 8) + threadIdx.x);
}
__global__ __launch_bounds__(256) void
k_aggf(const int* row_info, const int* srcs, const float* a_src, const float* a_dst,
       const unsigned int* hw, const float* bias, float* out, float* s_inv) {
    __shared__ int   s_lds[4][4][16];
    __shared__ float p_lds[4][4][16][4];
    phase_agg(row_info, srcs, a_src, a_dst, hw, bias, out, s_inv,
              s_lds, p_lds, gridDim.x, blockIdx.x, threadIdx.x);
}
__global__ __launch_bounds__(256) void
k_alphaf(const int* ei, const float* a_src, const float* a_dst,
         const float* s_inv, float* alpha_out) {
    phase_alpha(ei, a_src, a_dst, s_inv, alpha_out,
                gridDim.x << 8, (blockIdx.x << 8) + threadIdx.x);
}

extern "C" void kernel_launch(void* const* d_in, const int* in_sizes, int n_in,
                              void* d_out, int out_size, void* d_ws, size_t ws_size,
                              hipStream_t stream) {
    const float* x       = (const float*)d_in[0];
    const int*   ei      = (const int*)d_in[1];
    const float* W       = (const float*)d_in[2];
    const float* att_src = (const float*)d_in[3];
    const float* att_dst = (const float*)d_in[4];
    const float* bias    = (const float*)d_in[5];

    float* out       = (float*)d_out;
    float* alpha_out = (float*)d_out + (size_t)N_NODES * HC;

    char* ws = (char*)d_ws;
    size_t off = 0;
    unsigned short* hbf = (unsigned short*)(ws + off); off += (size_t)N_NODES * HC * 2; // 6.4 MB
    float* a_src   = (float*)(ws + off); off += (size_t)N_NODES * 4 * 4;
    float* a_dst   = (float*)(ws + off); off += (size_t)N_NODES * 4 * 4;
    float* s_inv   = (float*)(ws + off); off += (size_t)N_NODES * 4 * 4;
    int* row_info  = (int*)(ws + off);   off += (size_t)N_NODES * 4;
    int* srcs      = (int*)(ws + off);   off += (size_t)NBUCK * BCAP * 4;   // 4.0 MB
    int* deg       = (int*)(ws + off);   off += (size_t)N_NODES * 4;
    int* cur       = (int*)(ws + off);   off += (size_t)N_NODES * 4;

    kA_linear<<<LIN_BLOCKS, 256, 0, stream>>>(x, W, att_src, att_dst, hbf, a_src, a_dst);

    static int coop_ok = -1;   // -1 unknown, 1 works, 0 fallback
    if (coop_ok != 0) {
        const unsigned int* hw = (const unsigned int*)hbf;
        void* args[12] = {
            (void*)&ei, (void*)&a_src, (void*)&a_dst, (void*)&hw, (void*)&bias,
            (void*)&out, (void*)&s_inv, (void*)&deg, (void*)&cur,
            (void*)&row_info, (void*)&srcs, (void*)&alpha_out};
        hipError_t e = hipLaunchCooperativeKernel((void*)mega, dim3(MEGA_GRID),
                                                  dim3(256), args, 0, stream);
        coop_ok = (e == hipSuccess) ? 1 : 0;
    }
    if (coop_ok == 0) {
        k_zero<<<196, 256, 0, stream>>>(deg);
        k_count<<<782, 256, 0, stream>>>(ei, deg);
        k_scan<<<NBUCK, 256, 0, stream>>>(deg, row_info, srcs, cur);
        k_scatter<<<782, 256, 0, stream>>>(ei, cur, srcs);
        k_aggf<<<NAGG, 256, 0, stream>>>(row_info, srcs, a_src, a_dst,
                                         (const unsigned int*)hbf, bias, out, s_inv);
        k_alphaf<<<(NPAIR + 255) / 256, 256, 0, stream>>>(ei, a_src, a_dst, s_inv, alpha_out);
    }
}

// Round 2
// 85.660 us; speedup vs baseline: 1.7170x; 1.7170x over previous
//
#include <hip/hip_runtime.h>

#define N_NODES 50000
#define N_EDGES 800000
#define EN      (N_EDGES + N_NODES)
#define F_IN    128
#define HC      64    // HEADS * C_OUT
#define NEG_SLOPE 0.2f
#define NBUCK   196   // ceil(50000/256) buckets of 256 nodes
#define BCAP    5120  // per-bucket capacity in srcs
#define P3_EPB  4096  // edges per bin block
#define LIN_BLOCKS 782               // ceil(50000/64) -- 64 rows/block (MFMA)
#define NBLK    196                  // ceil(N_EDGES / P3_EPB) -- REAL edges only
#define RCAP    64                   // per-(block,bucket) region capacity (mean 21)
#define NSLOT   (NBLK * RCAP)        // 12544 slots per bucket
#define XPAD    136                  // LDS row stride in shorts (2-way conflicts only)

typedef __attribute__((ext_vector_type(8))) short bf16x8;
typedef __attribute__((ext_vector_type(4))) float f32x4;

static __device__ __forceinline__ unsigned short f2bf(float f) {   // RNE f32->bf16
    unsigned int b = __float_as_uint(f);
    return (unsigned short)((b + 0x7FFFu + ((b >> 16) & 1u)) >> 16);
}

// ---------------- KA: [blocks 0..781] h=x@W via bf16 MFMA + a_src/a_dst
//                  [blocks 782..977] region-binned scatter of REAL edges ----------
__global__ __launch_bounds__(256) void
kA_linear_bin(const float* __restrict__ x, const float* __restrict__ W,
              const float* __restrict__ att_src, const float* __restrict__ att_dst,
              const int* __restrict__ ei,
              unsigned short* __restrict__ hbf, float* __restrict__ a_src,
              float* __restrict__ a_dst, int* __restrict__ bins,
              int* __restrict__ cntg) {
    __shared__ unsigned short xs[64][XPAD];      // 17.4 KB bf16 x-tile
    __shared__ unsigned short wt[64][XPAD];      // 17.4 KB bf16 W^T (col-major W)
    __shared__ int bcnt_l[NBUCK];
    const int tid = threadIdx.x;

    if (blockIdx.x >= LIN_BLOCKS) {
        // ---- binning branch: real edges only, fixed regions, no global atomics ----
        const int blk = blockIdx.x - LIN_BLOCKS;
        for (int i = tid; i < NBUCK; i += 256) bcnt_l[i] = 0;
        __syncthreads();
        const int base = blk * P3_EPB;
        #pragma unroll
        for (int j = 0; j < 16; ++j) {
            int i = base + j * 256 + tid;
            if (i < N_EDGES) {
                int sv = ei[i];
                int d  = ei[N_EDGES + i];
                int bk = d >> 8;
                int r  = atomicAdd(&bcnt_l[bk], 1);
                if (r < RCAP)
                    bins[(bk * NBLK + blk) * RCAP + r] = sv | ((d & 255) << 16);
            }
        }
        __syncthreads();
        for (int b = tid; b < NBUCK; b += 256)
            cntg[b * NBLK + blk] = min(bcnt_l[b], RCAP);
        return;
    }

    // ---- linear branch: 64 rows per block, 16 rows per wave, MFMA 16x16x32 ----
    const int wv   = tid >> 6;
    const int l    = tid & 63;
    const int base = blockIdx.x * 64;
    const int c16  = l & 15;        // MFMA non-K lane index
    const int grp  = l >> 4;        // K-group / C row-group

    // stage W transposed as bf16: wt[col][k]  (8 coalesced float4 loads/thread)
    #pragma unroll
    for (int it = 0; it < 8; ++it) {
        int f  = it * 1024 + tid * 4;   // covers 128*64 = 8192 floats
        int k  = f >> 6;                // W row (K index)
        int cl = f & 63;                // W col
        float4 v = *(const float4*)(W + (size_t)k * HC + cl);
        wt[cl + 0][k] = f2bf(v.x);
        wt[cl + 1][k] = f2bf(v.y);
        wt[cl + 2][k] = f2bf(v.z);
        wt[cl + 3][k] = f2bf(v.w);
    }

    // stage x-tile (64 x 128) as bf16
    #pragma unroll
    for (int it = 0; it < 8; ++it) {
        int f   = it * 1024 + tid * 4;
        int row = f >> 7, k = f & 127;
        int gr  = base + row;
        float4 v = {0.f, 0.f, 0.f, 0.f};
        if (gr < N_NODES) v = *(const float4*)(x + (size_t)gr * F_IN + k);
        ushort4 u = {f2bf(v.x), f2bf(v.y), f2bf(v.z), f2bf(v.w)};
        *(ushort4*)(&xs[row][k]) = u;
    }
    __syncthreads();

    // B-frags via ds_read_b128: lane col=c16 of tile t, k=kk*32+grp*8..+7
    bf16x8 Bf[4][4];
    #pragma unroll
    for (int t = 0; t < 4; ++t)
        #pragma unroll
        for (int kk = 0; kk < 4; ++kk)
            Bf[t][kk] = *(const bf16x8*)(&wt[t * 16 + c16][kk * 32 + grp * 8]);

    // A-frags for this wave's 16 rows: lane row=c16, k=kk*32+grp*8..+7
    const int r0 = wv * 16;
    f32x4 C[4];
    #pragma unroll
    for (int t = 0; t < 4; ++t) C[t] = (f32x4){0.f, 0.f, 0.f, 0.f};
    bf16x8 A[4];
    #pragma unroll
    for (int kk = 0; kk < 4; ++kk)
        A[kk] = *(const bf16x8*)(&xs[r0 + c16][kk * 32 + grp * 8]);
    #pragma unroll
    for (int t = 0; t < 4; ++t)
        #pragma unroll
        for (int kk = 0; kk < 4; ++kk)
            C[t] = __builtin_amdgcn_mfma_f32_16x16x32_bf16(A[kk], Bf[t][kk], C[t], 0, 0, 0);

    // epilogue: C lane holds rows grp*4+j, col t*16+c16
    float asv[4], adv[4];
    #pragma unroll
    for (int t = 0; t < 4; ++t) {
        asv[t] = att_src[t * 16 + c16];
        adv[t] = att_dst[t * 16 + c16];
    }
    #pragma unroll
    for (int j = 0; j < 4; ++j) {
        const int row = base + r0 + grp * 4 + j;
        const bool ok = row < N_NODES;
        float4 ta, td;
        float* tap = (float*)&ta;
        float* tdp = (float*)&td;
        #pragma unroll
        for (int t = 0; t < 4; ++t) {
            const float hv = C[t][j];
            if (ok) hbf[(size_t)row * HC + t * 16 + c16] = f2bf(hv);
            float ts = hv * asv[t];
            float tdv = hv * adv[t];
            #pragma unroll
            for (int m = 1; m < 16; m <<= 1) {
                ts  += __shfl_xor(ts, m);
                tdv += __shfl_xor(tdv, m);
            }
            tap[t] = ts;
            tdp[t] = tdv;
        }
        if (ok && c16 == 0) {
            *(float4*)(a_src + row * 4) = ta;
            *(float4*)(a_dst + row * 4) = td;
        }
    }
}

// ---------------- P4: per-bucket CSR; self-loop synthesized per node ----------------
__global__ __launch_bounds__(256) void
p4_csr(const int* __restrict__ bins, const int* __restrict__ cntg,
       int* __restrict__ row_info, int* __restrict__ srcs) {
    __shared__ int cntrow[NBLK];
    __shared__ int cnt[256], sm[256], cur[256];
    const int b = blockIdx.x, tid = threadIdx.x;
    const int node = (b << 8) + tid;

    if (tid < NBLK) cntrow[tid] = cntg[b * NBLK + tid];
    cnt[tid] = (node < N_NODES) ? 1 : 0;          // the self-loop
    __syncthreads();

    const int* bb = bins + (size_t)b * NSLOT;
    for (int slot = tid; slot < NSLOT; slot += 256) {
        int blk = slot >> 6;                       // RCAP = 64
        int k   = slot & (RCAP - 1);
        if (k < cntrow[blk]) atomicAdd(&cnt[bb[slot] >> 16], 1);
    }
    __syncthreads();

    int v = cnt[tid];
    sm[tid] = v;
    __syncthreads();
    for (int off = 1; off < 256; off <<= 1) {
        int t = (tid >= off) ? sm[tid - off] : 0;
        __syncthreads();
        sm[tid] += t;
        __syncthreads();
    }
    const int ex = sm[tid] - v;
    const int sbase = b * BCAP;

    if (node < N_NODES) {
        row_info[node] = ((sbase + ex) << 8) | v;  // deg <= 255
        srcs[sbase + ex] = node;                   // self-loop at segment head
    }
    cur[tid] = ex + 1;
    __syncthreads();
    for (int slot = tid; slot < NSLOT; slot += 256) {
        int blk = slot >> 6;
        int k   = slot & (RCAP - 1);
        if (k < cntrow[blk]) {
            int pv = bb[slot];
            int p  = atomicAdd(&cur[pv >> 16], 1);
            srcs[sbase + p] = pv & 0xFFFF;
        }
    }
}

// 16-entry fast path: all gathers issued before any consume (deep MLP).
// Statically indexed arrays -> registers (no scratch).
static __device__ __forceinline__ void
gath16(const unsigned int* __restrict__ hw, const int* __restrict__ sl,
       const float (*__restrict__ pl)[4], int hd, int l,
       float& a0, float& a1, float& a2, float& a3) {
    int   ss[16];
    uint2 uu[16];
    float pp[16];
    #pragma unroll
    for (int e = 0; e < 16; ++e) ss[e] = sl[e];
    #pragma unroll
    for (int e = 0; e < 16; ++e)
        uu[e] = *(const uint2*)(hw + (size_t)ss[e] * 32 + l * 2);
    #pragma unroll
    for (int e = 0; e < 16; ++e) pp[e] = pl[e][hd];
    #pragma unroll
    for (int e = 0; e < 16; ++e) {
        a0 += __uint_as_float(uu[e].x << 16)         * pp[e];
        a1 += __uint_as_float(uu[e].x & 0xFFFF0000u) * pp[e];
        a2 += __uint_as_float(uu[e].y << 16)         * pp[e];
        a3 += __uint_as_float(uu[e].y & 0xFFFF0000u) * pp[e];
    }
}

// ---------------- K3: single-pass softmax+agg; 16 lanes/dst; deep-MLP gather ------
__global__ __launch_bounds__(256) void
k_agg(const int* __restrict__ row_info, const int* __restrict__ srcs,
      const float* __restrict__ a_src, const float* __restrict__ a_dst,
      const unsigned int* __restrict__ hw,   // hbf as uint (2 bf16/word)
      const float* __restrict__ bias, float* __restrict__ out,
      float* __restrict__ s_inv) {
    __shared__ int   s_lds[4][4][16];
    __shared__ float p_lds[4][4][16][4];

    const int tid  = threadIdx.x;
    const int wv   = tid >> 6;
    const int lane = tid & 63;
    const int g    = lane >> 4;
    const int l    = lane & 15;
    const int hd   = l >> 2;
    const int d    = blockIdx.x * 16 + wv * 4 + g;   // grid = 3125

    const int info   = row_info[d];
    const int begin  = info >> 8;
    const int cnt    = info & 255;
    const int nchunk = (cnt + 15) >> 4;
    const float4 ad  = *(const float4*)(a_dst + d * 4);

    float4 ps = {0.f, 0.f, 0.f, 0.f};
    float a0 = 0.f, a1 = 0.f, a2 = 0.f, a3 = 0.f;

    for (int c = 0; c < nchunk; ++c) {
        const int k0 = begin + c * 16;
        const int m  = min(16, begin + cnt - k0);
        const int s = srcs[k0 + (l < m ? l : m - 1)];  // dup-src padding
        float4 p = {0.f, 0.f, 0.f, 0.f};
        if (l < m) {
            float4 as = *(const float4*)(a_src + s * 4);
            float e0 = as.x + ad.x, e1 = as.y + ad.y, e2 = as.z + ad.z, e3 = as.w + ad.w;
            e0 = e0 > 0.f ? e0 : NEG_SLOPE * e0;
            e1 = e1 > 0.f ? e1 : NEG_SLOPE * e1;
            e2 = e2 > 0.f ? e2 : NEG_SLOPE * e2;
            e3 = e3 > 0.f ? e3 : NEG_SLOPE * e3;
            p.x = __expf(e0); p.y = __expf(e1); p.z = __expf(e2); p.w = __expf(e3);
            ps.x += p.x; ps.y += p.y; ps.z += p.z; ps.w += p.w;
        }
        s_lds[wv][g][l] = s;
        *(float4*)(&p_lds[wv][g][l][0]) = p;
        __threadfence_block();

        const int mp = (m + 3) & ~3;                 // padded count (4,8,12,16)
        if (mp == 16) {
            // dominant path (~94% of gathered bytes): 16 loads in flight
            gath16(hw, s_lds[wv][g], p_lds[wv][g], hd, l, a0, a1, a2, a3);
        } else {
            for (int e = 0; e < mp; e += 4) {
                int s0 = s_lds[wv][g][e + 0], s1 = s_lds[wv][g][e + 1];
                int s2 = s_lds[wv][g][e + 2], s3 = s_lds[wv][g][e + 3];
                float p0 = p_lds[wv][g][e + 0][hd], p1 = p_lds[wv][g][e + 1][hd];
                float p2 = p_lds[wv][g][e + 2][hd], p3 = p_lds[wv][g][e + 3][hd];
                uint2 u0 = *(const uint2*)(hw + (size_t)s0 * 32 + l * 2);
                uint2 u1 = *(const uint2*)(hw + (size_t)s1 * 32 + l * 2);
                uint2 u2 = *(const uint2*)(hw + (size_t)s2 * 32 + l * 2);
                uint2 u3 = *(const uint2*)(hw + (size_t)s3 * 32 + l * 2);
                a0 += __uint_as_float(u0.x << 16)         * p0;
                a1 += __uint_as_float(u0.x & 0xFFFF0000u) * p0;
                a2 += __uint_as_float(u0.y << 16)         * p0;
                a3 += __uint_as_float(u0.y & 0xFFFF0000u) * p0;
                a0 += __uint_as_float(u1.x << 16)         * p1;
                a1 += __uint_as_float(u1.x & 0xFFFF0000u) * p1;
                a2 += __uint_as_float(u1.y << 16)         * p1;
                a3 += __uint_as_float(u1.y & 0xFFFF0000u) * p1;
                a0 += __uint_as_float(u2.x << 16)         * p2;
                a1 += __uint_as_float(u2.x & 0xFFFF0000u) * p2;
                a2 += __uint_as_float(u2.y << 16)         * p2;
                a3 += __uint_as_float(u2.y & 0xFFFF0000u) * p2;
                a0 += __uint_as_float(u3.x << 16)         * p3;
                a1 += __uint_as_float(u3.x & 0xFFFF0000u) * p3;
                a2 += __uint_as_float(u3.y << 16)         * p3;
                a3 += __uint_as_float(u3.y & 0xFFFF0000u) * p3;
            }
        }
        __threadfence_block();
    }

    #pragma unroll
    for (int mm = 1; mm < 16; mm <<= 1) {
        ps.x += __shfl_xor(ps.x, mm);
        ps.y += __shfl_xor(ps.y, mm);
        ps.z += __shfl_xor(ps.z, mm);
        ps.w += __shfl_xor(ps.w, mm);
    }
    const float4 inv = {1.f / (ps.x + 1e-16f), 1.f / (ps.y + 1e-16f),
                        1.f / (ps.z + 1e-16f), 1.f / (ps.w + 1e-16f)};
    if (l == 0) *(float4*)(s_inv + d * 4) = inv;

    const float invh = (hd == 0) ? inv.x : (hd == 1) ? inv.y : (hd == 2) ? inv.z : inv.w;
    float4 o;
    o.x = a0 * invh + bias[l * 4 + 0];
    o.y = a1 * invh + bias[l * 4 + 1];
    o.z = a2 * invh + bias[l * 4 + 2];
    o.w = a3 * invh + bias[l * 4 + 3];
    *(float4*)(out + (size_t)d * HC + l * 4) = o;
}

// ---------------- K4: alpha in ORIGINAL edge order; 2 edges/thread ----------------
__global__ void k_alpha(const int* __restrict__ ei, const float* __restrict__ a_src,
                        const float* __restrict__ a_dst, const float* __restrict__ s_inv,
                        float* __restrict__ alpha_out) {
    int i2 = blockIdx.x * 256 + threadIdx.x;
    if (i2 >= EN / 2) return;                 // EN even
    const int i = i2 * 2;
    int s0, s1, d0, d1;
    if (i < N_EDGES) {                        // N_EDGES even: pair never straddles
        int2 sp = *(const int2*)(ei + i);
        int2 dp = *(const int2*)(ei + N_EDGES + i);
        s0 = sp.x; s1 = sp.y; d0 = dp.x; d1 = dp.y;
    } else {
        s0 = d0 = i - N_EDGES;
        s1 = d1 = i + 1 - N_EDGES;
    }

    float4 as0 = *(const float4*)(a_src + s0 * 4);
    float4 ad0 = *(const float4*)(a_dst + d0 * 4);
    float4 iv0 = *(const float4*)(s_inv + d0 * 4);
    float4 as1 = *(const float4*)(a_src + s1 * 4);
    float4 ad1 = *(const float4*)(a_dst + d1 * 4);
    float4 iv1 = *(const float4*)(s_inv + d1 * 4);

    float e0, e1, e2, e3;
    e0 = as0.x + ad0.x; e1 = as0.y + ad0.y; e2 = as0.z + ad0.z; e3 = as0.w + ad0.w;
    e0 = e0 > 0.f ? e0 : NEG_SLOPE * e0;
    e1 = e1 > 0.f ? e1 : NEG_SLOPE * e1;
    e2 = e2 > 0.f ? e2 : NEG_SLOPE * e2;
    e3 = e3 > 0.f ? e3 : NEG_SLOPE * e3;
    float4 al0 = {__expf(e0) * iv0.x, __expf(e1) * iv0.y,
                  __expf(e2) * iv0.z, __expf(e3) * iv0.w};
    e0 = as1.x + ad1.x; e1 = as1.y + ad1.y; e2 = as1.z + ad1.z; e3 = as1.w + ad1.w;
    e0 = e0 > 0.f ? e0 : NEG_SLOPE * e0;
    e1 = e1 > 0.f ? e1 : NEG_SLOPE * e1;
    e2 = e2 > 0.f ? e2 : NEG_SLOPE * e2;
    e3 = e3 > 0.f ? e3 : NEG_SLOPE * e3;
    float4 al1 = {__expf(e0) * iv1.x, __expf(e1) * iv1.y,
                  __expf(e2) * iv1.z, __expf(e3) * iv1.w};

    *(float4*)(alpha_out + (size_t)i * 4)     = al0;
    *(float4*)(alpha_out + (size_t)i * 4 + 4) = al1;
}

extern "C" void kernel_launch(void* const* d_in, const int* in_sizes, int n_in,
                              void* d_out, int out_size, void* d_ws, size_t ws_size,
                              hipStream_t stream) {
    const float* x       = (const float*)d_in[0];
    const int*   ei      = (const int*)d_in[1];
    const float* W       = (const float*)d_in[2];
    const float* att_src = (const float*)d_in[3];
    const float* att_dst = (const float*)d_in[4];
    const float* bias    = (const float*)d_in[5];

    float* out       = (float*)d_out;
    float* alpha_out = (float*)d_out + (size_t)N_NODES * HC;

    char* ws = (char*)d_ws;
    size_t off = 0;
    unsigned short* hbf = (unsigned short*)(ws + off); off += (size_t)N_NODES * HC * 2; // 6.4 MB
    float* a_src   = (float*)(ws + off); off += (size_t)N_NODES * 4 * 4;
    float* a_dst   = (float*)(ws + off); off += (size_t)N_NODES * 4 * 4;
    float* s_inv   = (float*)(ws + off); off += (size_t)N_NODES * 4 * 4;
    int* row_info  = (int*)(ws + off);   off += (size_t)N_NODES * 4;
    int* srcs      = (int*)(ws + off);   off += (size_t)NBUCK * BCAP * 4;   // 4.0 MB
    int* bins      = (int*)(ws + off);   off += (size_t)NBUCK * NSLOT * 4;  // 9.8 MB
    int* cntg      = (int*)(ws + off);   off += (size_t)NBUCK * NBLK * 4;   // 154 KB

    kA_linear_bin<<<LIN_BLOCKS + NBLK, 256, 0, stream>>>(x, W, att_src, att_dst, ei,
                                                         hbf, a_src, a_dst, bins, cntg);
    p4_csr<<<NBUCK, 256, 0, stream>>>(bins, cntg, row_info, srcs);
    k_agg<<<N_NODES / 16, 256, 0, stream>>>(row_info, srcs, a_src, a_dst,
                                            (const unsigned int*)hbf, bias, out, s_inv);
    k_alpha<<<(EN / 2 + 255) / 256, 256, 0, stream>>>(ei, a_src, a_dst, s_inv, alpha_out);
}

// Round 3
// 80.927 us; speedup vs baseline: 1.8174x; 1.0585x over previous
//
#include <hip/hip_runtime.h>

#define N_NODES 50000
#define N_EDGES 800000
#define EN      (N_EDGES + N_NODES)
#define F_IN    128
#define HC      64    // HEADS * C_OUT
#define NEG_SLOPE 0.2f
#define NBUCK   196   // ceil(50000/256) buckets of 256 nodes
#define BCAP    5120  // per-bucket capacity in srcs
#define P3_EPB  4096  // edges per bin block
#define LIN_BLOCKS 782               // ceil(50000/64) -- 64 rows/block (MFMA)
#define NBLK    196                  // ceil(N_EDGES / P3_EPB) -- REAL edges only
#define RCAP    64                   // per-(block,bucket) region capacity (mean 21)
#define NSLOT   (NBLK * RCAP)        // 12544 slots per bucket
#define XPAD    136                  // LDS row stride in shorts (2-way conflicts only)

typedef __attribute__((ext_vector_type(8))) short bf16x8;
typedef __attribute__((ext_vector_type(4))) float f32x4;

static __device__ __forceinline__ unsigned short f2bf(float f) {   // RNE f32->bf16
    unsigned int b = __float_as_uint(f);
    return (unsigned short)((b + 0x7FFFu + ((b >> 16) & 1u)) >> 16);
}

// ---------------- KA: [blocks 0..781] h=x@W via bf16 MFMA; a_src/a_dst folded
//                  into the GEMM as a 5th B-tile (Wa = W@att^T, 8 cols).
//                  [blocks 782..977] region-binned scatter of REAL edges ----------
__global__ __launch_bounds__(256) void
kA_linear_bin(const float* __restrict__ x, const float* __restrict__ W,
              const float* __restrict__ att_src, const float* __restrict__ att_dst,
              const int* __restrict__ ei,
              unsigned short* __restrict__ hbf, float* __restrict__ a_src,
              float* __restrict__ a_dst, int* __restrict__ bins,
              int* __restrict__ cntg) {
    __shared__ unsigned short xs[64][XPAD];      // 17.4 KB bf16 x-tile
    __shared__ unsigned short wt[80][XPAD];      // cols 0..63 = W^T, 64..71 = Wa^T,
                                                 // 72..79 uninit (B cols 8..15 unused)
    __shared__ int bcnt_l[NBUCK];
    const int tid = threadIdx.x;

    if (blockIdx.x >= LIN_BLOCKS) {
        // ---- binning branch: real edges only, fixed regions, no global atomics ----
        const int blk = blockIdx.x - LIN_BLOCKS;
        for (int i = tid; i < NBUCK; i += 256) bcnt_l[i] = 0;
        __syncthreads();
        const int base = blk * P3_EPB;
        #pragma unroll
        for (int j = 0; j < 16; ++j) {
            int i = base + j * 256 + tid;
            if (i < N_EDGES) {
                int sv = ei[i];
                int d  = ei[N_EDGES + i];
                int bk = d >> 8;
                int r  = atomicAdd(&bcnt_l[bk], 1);
                if (r < RCAP)
                    bins[(bk * NBLK + blk) * RCAP + r] = sv | ((d & 255) << 16);
            }
        }
        __syncthreads();
        for (int b = tid; b < NBUCK; b += 256)
            cntg[b * NBLK + blk] = min(bcnt_l[b], RCAP);
        return;
    }

    // ---- linear branch: 64 rows per block, 16 rows per wave, MFMA 16x16x32 ----
    const int wv   = tid >> 6;
    const int l    = tid & 63;
    const int base = blockIdx.x * 64;
    const int c16  = l & 15;        // MFMA non-K lane index
    const int grp  = l >> 4;        // K-group / C row-group

    // stage W transposed as bf16: wt[col][k]  (8 coalesced float4 loads/thread)
    #pragma unroll
    for (int it = 0; it < 8; ++it) {
        int f  = it * 1024 + tid * 4;   // covers 128*64 = 8192 floats
        int k  = f >> 6;                // W row (K index)
        int cl = f & 63;                // W col
        float4 v = *(const float4*)(W + (size_t)k * HC + cl);
        wt[cl + 0][k] = f2bf(v.x);
        wt[cl + 1][k] = f2bf(v.y);
        wt[cl + 2][k] = f2bf(v.z);
        wt[cl + 3][k] = f2bf(v.w);
    }

    // stage x-tile (64 x 128) as bf16
    #pragma unroll
    for (int it = 0; it < 8; ++it) {
        int f   = it * 1024 + tid * 4;
        int row = f >> 7, k = f & 127;
        int gr  = base + row;
        float4 v = {0.f, 0.f, 0.f, 0.f};
        if (gr < N_NODES) v = *(const float4*)(x + (size_t)gr * F_IN + k);
        ushort4 u = {f2bf(v.x), f2bf(v.y), f2bf(v.z), f2bf(v.w)};
        *(ushort4*)(&xs[row][k]) = u;
    }

    // Wa columns: wt[64+o][k] = sum_c W[k][h*16+c] * att_{src|dst}[h][c]
    // o=0..3 -> att_src heads, o=4..7 -> att_dst heads. 4 entries/thread.
    {
        const int wk = tid >> 1;          // k = 0..127
        const int wo = (tid & 1) * 4;     // o base: 0 or 4
        const float* wrow = W + (size_t)wk * HC;
        #pragma unroll
        for (int oo = 0; oo < 4; ++oo) {
            const int o = wo + oo;
            const int h = o & 3;
            const float* av = (o < 4) ? (att_src + h * 16) : (att_dst + h * 16);
            float a = 0.f;
            #pragma unroll
            for (int c = 0; c < 16; c += 4) {
                float4 w4 = *(const float4*)(wrow + h * 16 + c);
                float4 a4 = *(const float4*)(av + c);
                a += w4.x * a4.x + w4.y * a4.y + w4.z * a4.z + w4.w * a4.w;
            }
            wt[64 + o][wk] = f2bf(a);
        }
    }
    __syncthreads();

    // B-frags via ds_read_b128: lane col=c16 of tile t, k=kk*32+grp*8..+7
    bf16x8 Bf[5][4];
    #pragma unroll
    for (int t = 0; t < 5; ++t)
        #pragma unroll
        for (int kk = 0; kk < 4; ++kk)
            Bf[t][kk] = *(const bf16x8*)(&wt[t * 16 + c16][kk * 32 + grp * 8]);

    // A-frags for this wave's 16 rows: lane row=c16, k=kk*32+grp*8..+7
    const int r0 = wv * 16;
    f32x4 C[4], C4;
    #pragma unroll
    for (int t = 0; t < 4; ++t) C[t] = (f32x4){0.f, 0.f, 0.f, 0.f};
    C4 = (f32x4){0.f, 0.f, 0.f, 0.f};
    bf16x8 A[4];
    #pragma unroll
    for (int kk = 0; kk < 4; ++kk)
        A[kk] = *(const bf16x8*)(&xs[r0 + c16][kk * 32 + grp * 8]);
    #pragma unroll
    for (int t = 0; t < 4; ++t)
        #pragma unroll
        for (int kk = 0; kk < 4; ++kk)
            C[t] = __builtin_amdgcn_mfma_f32_16x16x32_bf16(A[kk], Bf[t][kk], C[t], 0, 0, 0);
    #pragma unroll
    for (int kk = 0; kk < 4; ++kk)
        C4 = __builtin_amdgcn_mfma_f32_16x16x32_bf16(A[kk], Bf[4][kk], C4, 0, 0, 0);

    // epilogue: C lane holds rows grp*4+j, col t*16+c16. No shfl needed:
    // tile 4 col c16<4 -> a_src head c16; col 4..7 -> a_dst head c16-4.
    #pragma unroll
    for (int j = 0; j < 4; ++j) {
        const int row = base + r0 + grp * 4 + j;
        if (row < N_NODES) {
            #pragma unroll
            for (int t = 0; t < 4; ++t)
                hbf[(size_t)row * HC + t * 16 + c16] = f2bf(C[t][j]);
            if (c16 < 4)      a_src[row * 4 + c16]       = C4[j];
            else if (c16 < 8) a_dst[row * 4 + (c16 - 4)] = C4[j];
        }
    }
}

// ---------------- P4: per-bucket CSR; compacted scan (valid entries only) ----------
__global__ __launch_bounds__(256) void
p4_csr(const int* __restrict__ bins, const int* __restrict__ cntg,
       int* __restrict__ row_info, int* __restrict__ srcs) {
    __shared__ int psum[256];                      // inclusive prefix of cntrow
    __shared__ int cnt[256], sm[256], cur[256];
    const int b = blockIdx.x, tid = threadIdx.x;
    const int node = (b << 8) + tid;

    psum[tid] = (tid < NBLK) ? cntg[b * NBLK + tid] : 0;
    cnt[tid] = (node < N_NODES) ? 1 : 0;          // the self-loop
    __syncthreads();
    for (int off = 1; off < 256; off <<= 1) {     // Hillis-Steele inclusive scan
        int t = (tid >= off) ? psum[tid - off] : 0;
        __syncthreads();
        psum[tid] += t;
        __syncthreads();
    }
    const int T = psum[255];                      // total valid entries (<= BCAP)
    const int* bb = bins + (size_t)b * NSLOT;

    // count pass over VALID entries only; cache entries in registers for scatter
    int pvs[20];                                  // 20*256 = BCAP
    #pragma unroll
    for (int it = 0; it < 20; ++it) {
        const int i = tid + it * 256;
        if (i < T) {
            int lo = 0, hi = NBLK - 1;            // psum[NBLK-1] = T > i
            while (lo < hi) { int mid = (lo + hi) >> 1;
                              if (psum[mid] > i) hi = mid; else lo = mid + 1; }
            const int k  = i - (lo ? psum[lo - 1] : 0);
            const int pv = bb[lo * RCAP + k];
            pvs[it] = pv;
            atomicAdd(&cnt[pv >> 16], 1);
        }
    }
    __syncthreads();

    int v = cnt[tid];
    sm[tid] = v;
    __syncthreads();
    for (int off = 1; off < 256; off <<= 1) {
        int t = (tid >= off) ? sm[tid - off] : 0;
        __syncthreads();
        sm[tid] += t;
        __syncthreads();
    }
    const int ex = sm[tid] - v;
    const int sbase = b * BCAP;

    if (node < N_NODES) {
        row_info[node] = ((sbase + ex) << 8) | v;  // deg <= 255
        srcs[sbase + ex] = node;                   // self-loop at segment head
    }
    cur[tid] = ex + 1;
    __syncthreads();
    #pragma unroll
    for (int it = 0; it < 20; ++it) {
        const int i = tid + it * 256;
        if (i < T) {
            const int pv = pvs[it];
            const int p  = atomicAdd(&cur[pv >> 16], 1);
            srcs[sbase + p] = pv & 0xFFFF;
        }
    }
}

// ---------------- K3: single-pass softmax+agg; 16 lanes/dst; 4-wide unrolled gather --
__global__ __launch_bounds__(256) void
k_agg(const int* __restrict__ row_info, const int* __restrict__ srcs,
      const float* __restrict__ a_src, const float* __restrict__ a_dst,
      const unsigned int* __restrict__ hw,   // hbf as uint (2 bf16/word)
      const float* __restrict__ bias, float* __restrict__ out,
      float* __restrict__ s_inv) {
    __shared__ int   s_lds[4][4][16];
    __shared__ float p_lds[4][4][16][4];

    const int tid  = threadIdx.x;
    const int wv   = tid >> 6;
    const int lane = tid & 63;
    const int g    = lane >> 4;
    const int l    = lane & 15;
    const int hd   = l >> 2;
    const int d    = blockIdx.x * 16 + wv * 4 + g;   // grid = 3125

    const int info   = row_info[d];
    const int begin  = info >> 8;
    const int cnt    = info & 255;
    const int nchunk = (cnt + 15) >> 4;
    const float4 ad  = *(const float4*)(a_dst + d * 4);

    float4 ps = {0.f, 0.f, 0.f, 0.f};
    float a0 = 0.f, a1 = 0.f, a2 = 0.f, a3 = 0.f;

    for (int c = 0; c < nchunk; ++c) {
        const int k0 = begin + c * 16;
        const int m  = min(16, begin + cnt - k0);
        const int s = srcs[k0 + (l < m ? l : m - 1)];  // dup-src padding
        float4 p = {0.f, 0.f, 0.f, 0.f};
        if (l < m) {
            float4 as = *(const float4*)(a_src + s * 4);
            float e0 = as.x + ad.x, e1 = as.y + ad.y, e2 = as.z + ad.z, e3 = as.w + ad.w;
            e0 = e0 > 0.f ? e0 : NEG_SLOPE * e0;
            e1 = e1 > 0.f ? e1 : NEG_SLOPE * e1;
            e2 = e2 > 0.f ? e2 : NEG_SLOPE * e2;
            e3 = e3 > 0.f ? e3 : NEG_SLOPE * e3;
            p.x = __expf(e0); p.y = __expf(e1); p.z = __expf(e2); p.w = __expf(e3);
            ps.x += p.x; ps.y += p.y; ps.z += p.z; ps.w += p.w;
        }
        s_lds[wv][g][l] = s;
        *(float4*)(&p_lds[wv][g][l][0]) = p;
        __threadfence_block();

        const int mp = (m + 3) & ~3;                 // padded count (4,8,12,16)
        for (int e = 0; e < mp; e += 4) {
            int s0 = s_lds[wv][g][e + 0], s1 = s_lds[wv][g][e + 1];
            int s2 = s_lds[wv][g][e + 2], s3 = s_lds[wv][g][e + 3];
            float p0 = p_lds[wv][g][e + 0][hd], p1 = p_lds[wv][g][e + 1][hd];
            float p2 = p_lds[wv][g][e + 2][hd], p3 = p_lds[wv][g][e + 3][hd];
            uint2 u0 = *(const uint2*)(hw + (size_t)s0 * 32 + l * 2);
            uint2 u1 = *(const uint2*)(hw + (size_t)s1 * 32 + l * 2);
            uint2 u2 = *(const uint2*)(hw + (size_t)s2 * 32 + l * 2);
            uint2 u3 = *(const uint2*)(hw + (size_t)s3 * 32 + l * 2);
            a0 += __uint_as_float(u0.x << 16)         * p0;
            a1 += __uint_as_float(u0.x & 0xFFFF0000u) * p0;
            a2 += __uint_as_float(u0.y << 16)         * p0;
            a3 += __uint_as_float(u0.y & 0xFFFF0000u) * p0;
            a0 += __uint_as_float(u1.x << 16)         * p1;
            a1 += __uint_as_float(u1.x & 0xFFFF0000u) * p1;
            a2 += __uint_as_float(u1.y << 16)         * p1;
            a3 += __uint_as_float(u1.y & 0xFFFF0000u) * p1;
            a0 += __uint_as_float(u2.x << 16)         * p2;
            a1 += __uint_as_float(u2.x & 0xFFFF0000u) * p2;
            a2 += __uint_as_float(u2.y << 16)         * p2;
            a3 += __uint_as_float(u2.y & 0xFFFF0000u) * p2;
            a0 += __uint_as_float(u3.x << 16)         * p3;
            a1 += __uint_as_float(u3.x & 0xFFFF0000u) * p3;
            a2 += __uint_as_float(u3.y << 16)         * p3;
            a3 += __uint_as_float(u3.y & 0xFFFF0000u) * p3;
        }
        __threadfence_block();
    }

    #pragma unroll
    for (int mm = 1; mm < 16; mm <<= 1) {
        ps.x += __shfl_xor(ps.x, mm);
        ps.y += __shfl_xor(ps.y, mm);
        ps.z += __shfl_xor(ps.z, mm);
        ps.w += __shfl_xor(ps.w, mm);
    }
    const float4 inv = {1.f / (ps.x + 1e-16f), 1.f / (ps.y + 1e-16f),
                        1.f / (ps.z + 1e-16f), 1.f / (ps.w + 1e-16f)};
    if (l == 0) *(float4*)(s_inv + d * 4) = inv;

    const float invh = (hd == 0) ? inv.x : (hd == 1) ? inv.y : (hd == 2) ? inv.z : inv.w;
    float4 o;
    o.x = a0 * invh + bias[l * 4 + 0];
    o.y = a1 * invh + bias[l * 4 + 1];
    o.z = a2 * invh + bias[l * 4 + 2];
    o.w = a3 * invh + bias[l * 4 + 3];
    *(float4*)(out + (size_t)d * HC + l * 4) = o;
}

// ---------------- K4: alpha in ORIGINAL edge order; 2 edges/thread ----------------
__global__ void k_alpha(const int* __restrict__ ei, const float* __restrict__ a_src,
                        const float* __restrict__ a_dst, const float* __restrict__ s_inv,
                        float* __restrict__ alpha_out) {
    int i2 = blockIdx.x * 256 + threadIdx.x;
    if (i2 >= EN / 2) return;                 // EN even
    const int i = i2 * 2;
    int s0, s1, d0, d1;
    if (i < N_EDGES) {                        // N_EDGES even: pair never straddles
        int2 sp = *(const int2*)(ei + i);
        int2 dp = *(const int2*)(ei + N_EDGES + i);
        s0 = sp.x; s1 = sp.y; d0 = dp.x; d1 = dp.y;
    } else {
        s0 = d0 = i - N_EDGES;
        s1 = d1 = i + 1 - N_EDGES;
    }

    float4 as0 = *(const float4*)(a_src + s0 * 4);
    float4 ad0 = *(const float4*)(a_dst + d0 * 4);
    float4 iv0 = *(const float4*)(s_inv + d0 * 4);
    float4 as1 = *(const float4*)(a_src + s1 * 4);
    float4 ad1 = *(const float4*)(a_dst + d1 * 4);
    float4 iv1 = *(const float4*)(s_inv + d1 * 4);

    float e0, e1, e2, e3;
    e0 = as0.x + ad0.x; e1 = as0.y + ad0.y; e2 = as0.z + ad0.z; e3 = as0.w + ad0.w;
    e0 = e0 > 0.f ? e0 : NEG_SLOPE * e0;
    e1 = e1 > 0.f ? e1 : NEG_SLOPE * e1;
    e2 = e2 > 0.f ? e2 : NEG_SLOPE * e2;
    e3 = e3 > 0.f ? e3 : NEG_SLOPE * e3;
    float4 al0 = {__expf(e0) * iv0.x, __expf(e1) * iv0.y,
                  __expf(e2) * iv0.z, __expf(e3) * iv0.w};
    e0 = as1.x + ad1.x; e1 = as1.y + ad1.y; e2 = as1.z + ad1.z; e3 = as1.w + ad1.w;
    e0 = e0 > 0.f ? e0 : NEG_SLOPE * e0;
    e1 = e1 > 0.f ? e1 : NEG_SLOPE * e1;
    e2 = e2 > 0.f ? e2 : NEG_SLOPE * e2;
    e3 = e3 > 0.f ? e3 : NEG_SLOPE * e3;
    float4 al1 = {__expf(e0) * iv1.x, __expf(e1) * iv1.y,
                  __expf(e2) * iv1.z, __expf(e3) * iv1.w};

    *(float4*)(alpha_out + (size_t)i * 4)     = al0;
    *(float4*)(alpha_out + (size_t)i * 4 + 4) = al1;
}

extern "C" void kernel_launch(void* const* d_in, const int* in_sizes, int n_in,
                              void* d_out, int out_size, void* d_ws, size_t ws_size,
                              hipStream_t stream) {
    const float* x       = (const float*)d_in[0];
    const int*   ei      = (const int*)d_in[1];
    const float* W       = (const float*)d_in[2];
    const float* att_src = (const float*)d_in[3];
    const float* att_dst = (const float*)d_in[4];
    const float* bias    = (const float*)d_in[5];

    float* out       = (float*)d_out;
    float* alpha_out = (float*)d_out + (size_t)N_NODES * HC;

    char* ws = (char*)d_ws;
    size_t off = 0;
    unsigned short* hbf = (unsigned short*)(ws + off); off += (size_t)N_NODES * HC * 2; // 6.4 MB
    float* a_src   = (float*)(ws + off); off += (size_t)N_NODES * 4 * 4;
    float* a_dst   = (float*)(ws + off); off += (size_t)N_NODES * 4 * 4;
    float* s_inv   = (float*)(ws + off); off += (size_t)N_NODES * 4 * 4;
    int* row_info  = (int*)(ws + off);   off += (size_t)N_NODES * 4;
    int* srcs      = (int*)(ws + off);   off += (size_t)NBUCK * BCAP * 4;   // 4.0 MB
    int* bins      = (int*)(ws + off);   off += (size_t)NBUCK * NSLOT * 4;  // 9.8 MB
    int* cntg      = (int*)(ws + off);   off += (size_t)NBUCK * NBLK * 4;   // 154 KB

    kA_linear_bin<<<LIN_BLOCKS + NBLK, 256, 0, stream>>>(x, W, att_src, att_dst, ei,
                                                         hbf, a_src, a_dst, bins, cntg);
    p4_csr<<<NBUCK, 256, 0, stream>>>(bins, cntg, row_info, srcs);
    k_agg<<<N_NODES / 16, 256, 0, stream>>>(row_info, srcs, a_src, a_dst,
                                            (const unsigned int*)hbf, bias, out, s_inv);
    k_alpha<<<(EN / 2 + 255) / 256, 256, 0, stream>>>(ei, a_src, a_dst, s_inv, alpha_out);
}